// Round 5
// baseline (340.793 us; speedup 1.0000x reference)
//
#include <hip/hip_runtime.h>
#include <hip/hip_bf16.h>
#include <math.h>

#define NPTS 16384
#define KNBR 16
#define EPSV 1e-5f

__device__ __forceinline__ float lrelu_(float x){ return fmaxf(x, 0.2f*x); }
__device__ __forceinline__ float rfl(float x){
    return __uint_as_float((unsigned)__builtin_amdgcn_readfirstlane(__float_as_uint(x)));
}
__device__ __forceinline__ unsigned pk2(float lo, float hi){
    __hip_bfloat16 a = __float2bfloat16(lo), b = __float2bfloat16(hi);
    unsigned short ua = *reinterpret_cast<unsigned short*>(&a);
    unsigned short ub = *reinterpret_cast<unsigned short*>(&b);
    return (unsigned)ua | ((unsigned)ub << 16);
}
__device__ __forceinline__ unsigned short f2bs(float x){
    __hip_bfloat16 a = __float2bfloat16(x);
    return *reinterpret_cast<unsigned short*>(&a);
}
__device__ __forceinline__ void unpk(unsigned u, float& lo, float& hi){
    lo = __uint_as_float(u << 16);
    hi = __uint_as_float(u & 0xffff0000u);
}

// ---------------- Kernel 1: f/q/k/v. 8 lanes/point, bf16 weights in LDS (~33KB). ----------------
// Lane ll owns rows o = 8i+ll (interleaved). LDS strides 20/36 uints -> conflict-free uint4 reads
// (window start = 20*ll % 32 resp. 4*ll, disjoint across the octet).
__global__ __launch_bounds__(256,3) void qkvf_kernel(
    const float* __restrict__ feature,
    const float* __restrict__ W1, const float* __restrict__ bn1,
    const float* __restrict__ Wq, const float* __restrict__ bq,
    const float* __restrict__ Wk, const float* __restrict__ bk,
    const float* __restrict__ Wv, const float* __restrict__ bv,
    float* __restrict__ f_ws, float* __restrict__ q_ws,
    unsigned short* __restrict__ kv_ws)
{
    __shared__ unsigned lw1h[64*20];
    __shared__ unsigned lwqh[64*36];
    __shared__ unsigned lwkh[64*36];
    __shared__ unsigned lwvh[64*36];
    __shared__ float lbq[64], lbk[64], lbv[64], ls1[64], lt1[64];

    const int t = threadIdx.x;
#pragma unroll
    for (int r=0;r<4;++r){
        const int idx = t + r*256;                 // 0..1023
        const int o = idx>>4, c2 = idx&15;
        lw1h[o*20+c2] = pk2(W1[o*32+2*c2], W1[o*32+2*c2+1]);
    }
#pragma unroll
    for (int r=0;r<8;++r){
        const int idx = t + r*256;                 // 0..2047
        const int o = idx>>5, c2 = idx&31;
        lwqh[o*36+c2] = pk2(Wq[o*64+2*c2], Wq[o*64+2*c2+1]);
        lwkh[o*36+c2] = pk2(Wk[o*64+2*c2], Wk[o*64+2*c2+1]);
        lwvh[o*36+c2] = pk2(Wv[o*64+2*c2], Wv[o*64+2*c2+1]);
    }
    if (t<64){
        lbq[t]=bq[t]; lbk[t]=bk[t]; lbv[t]=bv[t];
        const float s = bn1[t]*rsqrtf(bn1[192+t]+EPSV);
        ls1[t]=s; lt1[t]=fmaf(-bn1[128+t], s, bn1[64+t]);
    }
    __syncthreads();

    const int tid   = blockIdx.x*256 + t;          // 0 .. B*N*8-1
    const int ll    = t & 7;
    const int p     = tid >> 3;
    const int b     = p >> 14;
    const int n     = p & (NPTS-1);
    const int obase = (t & 63) & 56;

    // feature: lane loads input channels {8u+ll}
    float ft[4];
    const float* fbase = feature + b*32*NPTS + n;
#pragma unroll
    for (int u=0;u<4;++u) ft[u] = fbase[(8*u+ll)*NPTS];

    // exchange: Yfj[u] = feat[8u+j]
    float Yf0[4],Yf1[4],Yf2[4],Yf3[4],Yf4[4],Yf5[4],Yf6[4],Yf7[4];
#pragma unroll
    for (int u=0;u<4;++u){
        Yf0[u]=__shfl(ft[u], obase+0); Yf1[u]=__shfl(ft[u], obase+1);
        Yf2[u]=__shfl(ft[u], obase+2); Yf3[u]=__shfl(ft[u], obase+3);
        Yf4[u]=__shfl(ft[u], obase+4); Yf5[u]=__shfl(ft[u], obase+5);
        Yf6[u]=__shfl(ft[u], obase+6); Yf7[u]=__shfl(ft[u], obase+7);
    }

    // f = relu(bn1(W1@feat)), rows o=8i+ll
    float fv[8];
#pragma unroll
    for (int i=0;i<8;++i){
        const int o = 8*i+ll;
        const uint4* row = (const uint4*)(lw1h + o*20);
        float hs = 0.f;
#pragma unroll
        for (int g=0;g<4;++g){
            const uint4 w = row[g];
            float a,c;
            unpk(w.x,a,c); hs=fmaf(a,Yf0[g],hs); hs=fmaf(c,Yf1[g],hs);
            unpk(w.y,a,c); hs=fmaf(a,Yf2[g],hs); hs=fmaf(c,Yf3[g],hs);
            unpk(w.z,a,c); hs=fmaf(a,Yf4[g],hs); hs=fmaf(c,Yf5[g],hs);
            unpk(w.w,a,c); hs=fmaf(a,Yf6[g],hs); hs=fmaf(c,Yf7[g],hs);
        }
        fv[i] = fmaxf(fmaf(hs, ls1[o], lt1[o]), 0.f);
        f_ws[p*64+o] = fv[i];
    }

    // exchange: Yj[u] = f[8u+j]
    float Y0[8],Y1[8],Y2[8],Y3[8],Y4[8],Y5[8],Y6[8],Y7[8];
#pragma unroll
    for (int u=0;u<8;++u){
        Y0[u]=__shfl(fv[u], obase+0); Y1[u]=__shfl(fv[u], obase+1);
        Y2[u]=__shfl(fv[u], obase+2); Y3[u]=__shfl(fv[u], obase+3);
        Y4[u]=__shfl(fv[u], obase+4); Y5[u]=__shfl(fv[u], obase+5);
        Y6[u]=__shfl(fv[u], obase+6); Y7[u]=__shfl(fv[u], obase+7);
    }

#define QKV_ROWS(LWH, LBIAS, STORE_STMT)                              \
    _Pragma("unroll")                                                 \
    for (int i=0;i<8;++i){                                            \
        const int o = 8*i+ll;                                         \
        const uint4* row = (const uint4*)(LWH + o*36);                \
        float hs = LBIAS[o];                                          \
        _Pragma("unroll")                                             \
        for (int g=0;g<8;++g){                                        \
            const uint4 w = row[g];                                   \
            float a,c;                                                \
            unpk(w.x,a,c); hs=fmaf(a,Y0[g],hs); hs=fmaf(c,Y1[g],hs);  \
            unpk(w.y,a,c); hs=fmaf(a,Y2[g],hs); hs=fmaf(c,Y3[g],hs);  \
            unpk(w.z,a,c); hs=fmaf(a,Y4[g],hs); hs=fmaf(c,Y5[g],hs);  \
            unpk(w.w,a,c); hs=fmaf(a,Y6[g],hs); hs=fmaf(c,Y7[g],hs);  \
        }                                                             \
        STORE_STMT;                                                   \
    }

    QKV_ROWS(lwqh, lbq, q_ws[p*64+o] = hs)
    QKV_ROWS(lwkh, lbk, kv_ws[p*128+o] = f2bs(hs))
    QKV_ROWS(lwvh, lbv, kv_ws[p*128+64+o] = f2bs(hs))
#undef QKV_ROWS
}

// ---------------- Kernel 2: gather + attention + epilogue. 8 lanes/point. ----------------
__global__ __launch_bounds__(256,3) void attn_kernel(
    const float* __restrict__ xyz, const int* __restrict__ nidx,
    const float* __restrict__ Wp1, const float* __restrict__ bnp1,
    const float* __restrict__ Wp2, const float* __restrict__ bp2,
    const float* __restrict__ bnw0,
    const float* __restrict__ Ww1, const float* __restrict__ bnw1,
    const float* __restrict__ Ww2, const float* __restrict__ bw2,
    const float* __restrict__ bn_mid,
    const float* __restrict__ W2, const float* __restrict__ bn2,
    const float* __restrict__ f_ws, const float* __restrict__ q_ws,
    const unsigned short* __restrict__ kv_ws,
    float* __restrict__ out)
{
    __shared__ unsigned lww1h[8*32];   // Ww1 bf16-packed: row j, uint c2 = ch(2c2,2c2+1)
    __shared__ float lw2[64*68];       // W2 rows stride 68 -> conflict-free interleaved reads
    const int t = threadIdx.x;
    if (t < 256){
        const int j = t>>5, c2 = t&31;
        lww1h[j*32+c2] = pk2(Ww1[j*64+2*c2], Ww1[j*64+2*c2+1]);
    }
#pragma unroll
    for (int r=0;r<16;++r){
        const int idx = t + r*256;
        const int o = idx>>6, c = idx&63;
        lw2[o*68+c] = W2[idx];
    }
    __syncthreads();

    // XCD-bijective remap: XCDs 0-3 -> batch 0, XCDs 4-7 -> batch 1 (kv/batch = 4MB = one L2)
    const int rb  = (blockIdx.x & 7)*128 + (blockIdx.x >> 3);
    const int tid = rb*256 + t;
    const int ll  = t & 7;
    const int p   = tid >> 3;
    const int b   = p >> 14;
    const int n   = p & (NPTS-1);
    const int obase = (t & 63) & 56;

    // uniform constants -> SGPRs via readfirstlane
    float wp1[9];
#pragma unroll
    for (int u=0;u<9;++u) wp1[u] = rfl(Wp1[u]);
    float sp1[3], tp1[3];
#pragma unroll
    for (int o=0;o<3;++o){
        const float s = bnp1[o]*rsqrtf(bnp1[9+o]+EPSV);
        sp1[o]=rfl(s); tp1[o]=rfl(fmaf(-bnp1[6+o], s, bnp1[3+o]));
    }
    float sw1[8], tw1[8];
#pragma unroll
    for (int j=0;j<8;++j){
        const float s = bnw1[j]*rsqrtf(bnw1[24+j]+EPSV);
        sw1[j]=rfl(s); tw1[j]=rfl(fmaf(-bnw1[16+j], s, bnw1[8+j]));
    }
    // per-lane: Wp2 rows 8ll..8ll+7
    float wp2f[24];
#pragma unroll
    for (int u=0;u<6;++u){
        const float4 w = ((const float4*)Wp2)[6*ll+u];
        wp2f[4*u]=w.x; wp2f[4*u+1]=w.y; wp2f[4*u+2]=w.z; wp2f[4*u+3]=w.w;
    }
    // per-lane: Ww2 row ll
    float ww2r[8]; float bwr;
    {
        const float4 a = ((const float4*)Ww2)[2*ll], c = ((const float4*)Ww2)[2*ll+1];
        ww2r[0]=a.x; ww2r[1]=a.y; ww2r[2]=a.z; ww2r[3]=a.w;
        ww2r[4]=c.x; ww2r[5]=c.y; ww2r[6]=c.z; ww2r[7]=c.w;
        bwr = bw2[ll];
    }
    // fold bnw0 + q + bp2:  wl = lrelu(s0*(xk + prn) + qc)
    float s0[8], qc[8], bpv[8];
    {
        float qv[8];
        const float4* qp = (const float4*)(q_ws + p*64 + 8*ll);
        const float4 q0 = qp[0], q1 = qp[1];
        qv[0]=q0.x;qv[1]=q0.y;qv[2]=q0.z;qv[3]=q0.w; qv[4]=q1.x;qv[5]=q1.y;qv[6]=q1.z;qv[7]=q1.w;
        const float4* bp = (const float4*)(bp2 + 8*ll);
        const float4 b0 = bp[0], b1 = bp[1];
        bpv[0]=b0.x;bpv[1]=b0.y;bpv[2]=b0.z;bpv[3]=b0.w; bpv[4]=b1.x;bpv[5]=b1.y;bpv[6]=b1.z;bpv[7]=b1.w;
        const float4* g4 = (const float4*)(bnw0 + 8*ll);
        const float4 g0=g4[0], g1=g4[1];
        const float4* be4 = (const float4*)(bnw0 + 64 + 8*ll);
        const float4 e0=be4[0], e1=be4[1];
        const float4* m4 = (const float4*)(bnw0 + 128 + 8*ll);
        const float4 m0=m4[0], m1=m4[1];
        const float4* v4 = (const float4*)(bnw0 + 192 + 8*ll);
        const float4 v0=v4[0], v1=v4[1];
        const float gg[8]={g0.x,g0.y,g0.z,g0.w,g1.x,g1.y,g1.z,g1.w};
        const float bb[8]={e0.x,e0.y,e0.z,e0.w,e1.x,e1.y,e1.z,e1.w};
        const float mm[8]={m0.x,m0.y,m0.z,m0.w,m1.x,m1.y,m1.z,m1.w};
        const float vv[8]={v0.x,v0.y,v0.z,v0.w,v1.x,v1.y,v1.z,v1.w};
#pragma unroll
        for (int i=0;i<8;++i){
            const float s = gg[i]*rsqrtf(vv[i]+EPSV);
            s0[i]=s;
            qc[i]=fmaf(-mm[i], s, bb[i]) + s*(bpv[i]-qv[i]);
        }
    }

    float m[8], l[8], acc[8];
#pragma unroll
    for (int j=0;j<8;++j){ m[j]=-3.0e38f; l[j]=0.f; acc[j]=0.f; }

    const int* nip = nidx + p*16;

#pragma unroll 2
    for (int k=0;k<KNBR;++k){
        const int ni   = nip[k];
        const int rowb = (b<<14) + ni;
        const uint4* kvp = (const uint4*)(kv_ws + (size_t)rowb*128);
        const uint4 ku = kvp[ll];        // k channels 8ll..8ll+7 (bf16 x8)
        const uint4 vu = kvp[8+ll];      // v channels
        const float* xp = xyz + rowb*3;
        const float x0=xp[0], x1=xp[1], x2v=xp[2];

        float t3[3];
#pragma unroll
        for (int o=0;o<3;++o){
            const float u = fmaf(wp1[3*o], x0, fmaf(wp1[3*o+1], x1, wp1[3*o+2]*x2v));
            t3[o] = fmaxf(fmaf(u, sp1[o], tp1[o]), 0.f);
        }
        float kf[8];
        unpk(ku.x, kf[0], kf[1]); unpk(ku.y, kf[2], kf[3]);
        unpk(ku.z, kf[4], kf[5]); unpk(ku.w, kf[6], kf[7]);
        float pr[8], wl[8];
#pragma unroll
        for (int i=0;i<8;++i){
            pr[i] = fmaf(wp2f[3*i], t3[0], fmaf(wp2f[3*i+1], t3[1], wp2f[3*i+2]*t3[2]));
            wl[i] = lrelu_(fmaf(s0[i], kf[i]+pr[i], qc[i]));
        }
        // y_j = Ww1[j,:] . wl  (octet butterfly over 8 lanes)
        float y[8];
#pragma unroll
        for (int j=0;j<8;++j){
            const uint4 w = *(const uint4*)(lww1h + j*32 + 4*ll);
            float a,c, yy;
            unpk(w.x,a,c); yy  = a*wl[0];        yy = fmaf(c,wl[1],yy);
            unpk(w.y,a,c); yy = fmaf(a,wl[2],yy); yy = fmaf(c,wl[3],yy);
            unpk(w.z,a,c); yy = fmaf(a,wl[4],yy); yy = fmaf(c,wl[5],yy);
            unpk(w.w,a,c); yy = fmaf(a,wl[6],yy); yy = fmaf(c,wl[7],yy);
            yy += __shfl_xor(yy, 1);
            yy += __shfl_xor(yy, 2);
            yy += __shfl_xor(yy, 4);
            y[j] = yy;
        }
#pragma unroll
        for (int j=0;j<8;++j) y[j] = fmaxf(fmaf(y[j], sw1[j], tw1[j]), 0.f);
        float w2own = bwr;
#pragma unroll
        for (int j=0;j<8;++j) w2own = fmaf(ww2r[j], y[j], w2own);
        float w2[8];
        w2[0]=__shfl(w2own, obase+0); w2[1]=__shfl(w2own, obase+1);
        w2[2]=__shfl(w2own, obase+2); w2[3]=__shfl(w2own, obase+3);
        w2[4]=__shfl(w2own, obase+4); w2[5]=__shfl(w2own, obase+5);
        w2[6]=__shfl(w2own, obase+6); w2[7]=__shfl(w2own, obase+7);

        float sc[8], e[8];
#pragma unroll
        for (int j=0;j<8;++j){
            const float mn = fmaxf(m[j], w2[j]);
            sc[j] = __expf(m[j]-mn);
            e[j]  = __expf(w2[j]-mn);
            l[j]  = fmaf(l[j], sc[j], e[j]);
            m[j]  = mn;
        }
        float vf[8];
        unpk(vu.x, vf[0], vf[1]); unpk(vu.y, vf[2], vf[3]);
        unpk(vu.z, vf[4], vf[5]); unpk(vu.w, vf[6], vf[7]);
#pragma unroll
        for (int i=0;i<8;++i)
            acc[i] = fmaf(acc[i], sc[i], (vf[i]+pr[i])*e[i]);
    }

    // normalize + deferred bp2 + bn_mid + lrelu  (channels d = 8ll+i)
    float xm[8];
    {
        const float4* g4 = (const float4*)(bn_mid + 8*ll);
        const float4 g0=g4[0], g1=g4[1];
        const float4* be4 = (const float4*)(bn_mid + 64 + 8*ll);
        const float4 e0=be4[0], e1=be4[1];
        const float4* m4 = (const float4*)(bn_mid + 128 + 8*ll);
        const float4 m0=m4[0], m1=m4[1];
        const float4* v4 = (const float4*)(bn_mid + 192 + 8*ll);
        const float4 v0=v4[0], v1=v4[1];
        const float gg[8]={g0.x,g0.y,g0.z,g0.w,g1.x,g1.y,g1.z,g1.w};
        const float bb[8]={e0.x,e0.y,e0.z,e0.w,e1.x,e1.y,e1.z,e1.w};
        const float mm[8]={m0.x,m0.y,m0.z,m0.w,m1.x,m1.y,m1.z,m1.w};
        const float vv[8]={v0.x,v0.y,v0.z,v0.w,v1.x,v1.y,v1.z,v1.w};
#pragma unroll
        for (int i=0;i<8;++i){
            const float s = gg[i]*rsqrtf(vv[i]+EPSV);
            const float tt = fmaf(-mm[i], s, bb[i]);
            const float xx = fmaf(acc[i], 1.f/l[i], bpv[i]);
            xm[i] = lrelu_(fmaf(xx, s, tt));
        }
    }
    // exchange: Zx_g[r] = x[4g+r]
    float Zx0[4],Zx1[4],Zx2[4],Zx3[4],Zx4[4],Zx5[4],Zx6[4],Zx7[4];
    float Zx8[4],Zx9[4],Zx10[4],Zx11[4],Zx12[4],Zx13[4],Zx14[4],Zx15[4];
#pragma unroll
    for (int r=0;r<4;++r){
        Zx0[r] =__shfl(xm[r],   obase+0); Zx1[r] =__shfl(xm[4+r], obase+0);
        Zx2[r] =__shfl(xm[r],   obase+1); Zx3[r] =__shfl(xm[4+r], obase+1);
        Zx4[r] =__shfl(xm[r],   obase+2); Zx5[r] =__shfl(xm[4+r], obase+2);
        Zx6[r] =__shfl(xm[r],   obase+3); Zx7[r] =__shfl(xm[4+r], obase+3);
        Zx8[r] =__shfl(xm[r],   obase+4); Zx9[r] =__shfl(xm[4+r], obase+4);
        Zx10[r]=__shfl(xm[r],   obase+5); Zx11[r]=__shfl(xm[4+r], obase+5);
        Zx12[r]=__shfl(xm[r],   obase+6); Zx13[r]=__shfl(xm[4+r], obase+6);
        Zx14[r]=__shfl(xm[r],   obase+7); Zx15[r]=__shfl(xm[4+r], obase+7);
    }
#define DOT4(W4, Z) (fmaf((W4).w, (Z)[3], fmaf((W4).z, (Z)[2], fmaf((W4).y, (Z)[1], (W4).x*(Z)[0]))))
    const float* fpw = f_ws + p*64;
#pragma unroll
    for (int i=0;i<8;++i){
        const int o = 8*i+ll;
        const float4* row = (const float4*)(lw2 + o*68);
        float hs = 0.f;
        hs += DOT4(row[0],  Zx0);  hs += DOT4(row[1],  Zx1);
        hs += DOT4(row[2],  Zx2);  hs += DOT4(row[3],  Zx3);
        hs += DOT4(row[4],  Zx4);  hs += DOT4(row[5],  Zx5);
        hs += DOT4(row[6],  Zx6);  hs += DOT4(row[7],  Zx7);
        hs += DOT4(row[8],  Zx8);  hs += DOT4(row[9],  Zx9);
        hs += DOT4(row[10], Zx10); hs += DOT4(row[11], Zx11);
        hs += DOT4(row[12], Zx12); hs += DOT4(row[13], Zx13);
        hs += DOT4(row[14], Zx14); hs += DOT4(row[15], Zx15);
        const float s2 = bn2[o]*rsqrtf(bn2[192+o]+EPSV);
        const float t2 = fmaf(-bn2[128+o], s2, bn2[64+o]);
        const float x2r = fmaf(hs, s2, t2);
        out[(b*64+o)*NPTS + n] = lrelu_(fpw[o] + x2r);
    }
#undef DOT4
}

extern "C" void kernel_launch(void* const* d_in, const int* in_sizes, int n_in,
                              void* d_out, int out_size, void* d_ws, size_t ws_size,
                              hipStream_t stream) {
    const float* feature = (const float*)d_in[0];
    const float* xyz     = (const float*)d_in[1];
    const float* W1      = (const float*)d_in[2];
    const float* bn1     = (const float*)d_in[3];
    const float* Wq      = (const float*)d_in[4];
    const float* bq      = (const float*)d_in[5];
    const float* Wk      = (const float*)d_in[6];
    const float* bk      = (const float*)d_in[7];
    const float* Wv      = (const float*)d_in[8];
    const float* bv      = (const float*)d_in[9];
    const float* Wp1     = (const float*)d_in[10];
    const float* bnp1    = (const float*)d_in[11];
    const float* Wp2     = (const float*)d_in[12];
    const float* bp2     = (const float*)d_in[13];
    const float* bnw0    = (const float*)d_in[14];
    const float* Ww1     = (const float*)d_in[15];
    const float* bnw1    = (const float*)d_in[16];
    const float* Ww2     = (const float*)d_in[17];
    const float* bw2     = (const float*)d_in[18];
    const float* bn_mid  = (const float*)d_in[19];
    const float* W2      = (const float*)d_in[20];
    const float* bn2     = (const float*)d_in[21];
    const int*   nidx    = (const int*)d_in[22];
    float* out = (float*)d_out;

    // ws: f (8MB fp32) | q (8MB fp32) | kv (8MB bf16 packed, k||v per point)
    float* ws   = (float*)d_ws;
    float* f_ws = ws;
    float* q_ws = ws + 2097152;
    unsigned short* kv_ws = (unsigned short*)(ws + 4194304);

    qkvf_kernel<<<1024, 256, 0, stream>>>(feature, W1, bn1, Wq, bq, Wk, bk, Wv, bv,
                                          f_ws, q_ws, kv_ws);
    attn_kernel<<<1024, 256, 0, stream>>>(xyz, nidx, Wp1, bnp1, Wp2, bp2, bnw0,
                                          Ww1, bnw1, Ww2, bw2, bn_mid, W2, bn2,
                                          f_ws, q_ws, kv_ws, out);
}

// Round 6
// 338.919 us; speedup vs baseline: 1.0055x; 1.0055x over previous
//
#include <hip/hip_runtime.h>
#include <hip/hip_bf16.h>
#include <math.h>

#define NPTS 16384
#define KNBR 16
#define EPSV 1e-5f

__device__ __forceinline__ float lrelu_(float x){ return fmaxf(x, 0.2f*x); }
__device__ __forceinline__ float rfl(float x){
    return __uint_as_float((unsigned)__builtin_amdgcn_readfirstlane(__float_as_uint(x)));
}
__device__ __forceinline__ unsigned pk2(float lo, float hi){
    __hip_bfloat16 a = __float2bfloat16(lo), b = __float2bfloat16(hi);
    unsigned short ua = *reinterpret_cast<unsigned short*>(&a);
    unsigned short ub = *reinterpret_cast<unsigned short*>(&b);
    return (unsigned)ua | ((unsigned)ub << 16);
}
__device__ __forceinline__ unsigned short f2bs(float x){
    __hip_bfloat16 a = __float2bfloat16(x);
    return *reinterpret_cast<unsigned short*>(&a);
}
__device__ __forceinline__ void unpk(unsigned u, float& lo, float& hi){
    lo = __uint_as_float(u << 16);
    hi = __uint_as_float(u & 0xffff0000u);
}

// ---------------- Kernel 1: f/q/k/v. 8 lanes/point, bf16 weights in LDS (~33KB). ----------------
__global__ __launch_bounds__(256,3) void qkvf_kernel(
    const float* __restrict__ feature,
    const float* __restrict__ W1, const float* __restrict__ bn1,
    const float* __restrict__ Wq, const float* __restrict__ bq,
    const float* __restrict__ Wk, const float* __restrict__ bk,
    const float* __restrict__ Wv, const float* __restrict__ bv,
    float* __restrict__ f_ws, float* __restrict__ q_ws,
    unsigned short* __restrict__ kv_ws)
{
    __shared__ unsigned lw1h[64*20];
    __shared__ unsigned lwqh[64*36];
    __shared__ unsigned lwkh[64*36];
    __shared__ unsigned lwvh[64*36];
    __shared__ float lbq[64], lbk[64], lbv[64], ls1[64], lt1[64];

    const int t = threadIdx.x;
#pragma unroll
    for (int r=0;r<4;++r){
        const int idx = t + r*256;                 // 0..1023
        const int o = idx>>4, c2 = idx&15;
        lw1h[o*20+c2] = pk2(W1[o*32+2*c2], W1[o*32+2*c2+1]);
    }
#pragma unroll
    for (int r=0;r<8;++r){
        const int idx = t + r*256;                 // 0..2047
        const int o = idx>>5, c2 = idx&31;
        lwqh[o*36+c2] = pk2(Wq[o*64+2*c2], Wq[o*64+2*c2+1]);
        lwkh[o*36+c2] = pk2(Wk[o*64+2*c2], Wk[o*64+2*c2+1]);
        lwvh[o*36+c2] = pk2(Wv[o*64+2*c2], Wv[o*64+2*c2+1]);
    }
    if (t<64){
        lbq[t]=bq[t]; lbk[t]=bk[t]; lbv[t]=bv[t];
        const float s = bn1[t]*rsqrtf(bn1[192+t]+EPSV);
        ls1[t]=s; lt1[t]=fmaf(-bn1[128+t], s, bn1[64+t]);
    }
    __syncthreads();

    const int tid   = blockIdx.x*256 + t;          // 0 .. B*N*8-1
    const int ll    = t & 7;
    const int p     = tid >> 3;
    const int b     = p >> 14;
    const int n     = p & (NPTS-1);
    const int obase = (t & 63) & 56;

    float ft[4];
    const float* fbase = feature + b*32*NPTS + n;
#pragma unroll
    for (int u=0;u<4;++u) ft[u] = fbase[(8*u+ll)*NPTS];

    float Yf0[4],Yf1[4],Yf2[4],Yf3[4],Yf4[4],Yf5[4],Yf6[4],Yf7[4];
#pragma unroll
    for (int u=0;u<4;++u){
        Yf0[u]=__shfl(ft[u], obase+0); Yf1[u]=__shfl(ft[u], obase+1);
        Yf2[u]=__shfl(ft[u], obase+2); Yf3[u]=__shfl(ft[u], obase+3);
        Yf4[u]=__shfl(ft[u], obase+4); Yf5[u]=__shfl(ft[u], obase+5);
        Yf6[u]=__shfl(ft[u], obase+6); Yf7[u]=__shfl(ft[u], obase+7);
    }

    float fv[8];
#pragma unroll
    for (int i=0;i<8;++i){
        const int o = 8*i+ll;
        const uint4* row = (const uint4*)(lw1h + o*20);
        float hs = 0.f;
#pragma unroll
        for (int g=0;g<4;++g){
            const uint4 w = row[g];
            float a,c;
            unpk(w.x,a,c); hs=fmaf(a,Yf0[g],hs); hs=fmaf(c,Yf1[g],hs);
            unpk(w.y,a,c); hs=fmaf(a,Yf2[g],hs); hs=fmaf(c,Yf3[g],hs);
            unpk(w.z,a,c); hs=fmaf(a,Yf4[g],hs); hs=fmaf(c,Yf5[g],hs);
            unpk(w.w,a,c); hs=fmaf(a,Yf6[g],hs); hs=fmaf(c,Yf7[g],hs);
        }
        fv[i] = fmaxf(fmaf(hs, ls1[o], lt1[o]), 0.f);
        f_ws[p*64+o] = fv[i];
    }

    float Y0[8],Y1[8],Y2[8],Y3[8],Y4[8],Y5[8],Y6[8],Y7[8];
#pragma unroll
    for (int u=0;u<8;++u){
        Y0[u]=__shfl(fv[u], obase+0); Y1[u]=__shfl(fv[u], obase+1);
        Y2[u]=__shfl(fv[u], obase+2); Y3[u]=__shfl(fv[u], obase+3);
        Y4[u]=__shfl(fv[u], obase+4); Y5[u]=__shfl(fv[u], obase+5);
        Y6[u]=__shfl(fv[u], obase+6); Y7[u]=__shfl(fv[u], obase+7);
    }

#define QKV_ROWS(LWH, LBIAS, STORE_STMT)                              \
    _Pragma("unroll")                                                 \
    for (int i=0;i<8;++i){                                            \
        const int o = 8*i+ll;                                         \
        const uint4* row = (const uint4*)(LWH + o*36);                \
        float hs = LBIAS[o];                                          \
        _Pragma("unroll")                                             \
        for (int g=0;g<8;++g){                                        \
            const uint4 w = row[g];                                   \
            float a,c;                                                \
            unpk(w.x,a,c); hs=fmaf(a,Y0[g],hs); hs=fmaf(c,Y1[g],hs);  \
            unpk(w.y,a,c); hs=fmaf(a,Y2[g],hs); hs=fmaf(c,Y3[g],hs);  \
            unpk(w.z,a,c); hs=fmaf(a,Y4[g],hs); hs=fmaf(c,Y5[g],hs);  \
            unpk(w.w,a,c); hs=fmaf(a,Y6[g],hs); hs=fmaf(c,Y7[g],hs);  \
        }                                                             \
        STORE_STMT;                                                   \
    }

    QKV_ROWS(lwqh, lbq, q_ws[p*64+o] = hs)
    QKV_ROWS(lwkh, lbk, kv_ws[p*128+o] = f2bs(hs))
    QKV_ROWS(lwvh, lbv, kv_ws[p*128+64+o] = f2bs(hs))
#undef QKV_ROWS
}

// ---------------- Kernel 2: gather + attention + epilogue. 8 lanes/point. ----------------
__global__ __launch_bounds__(256,3) void attn_kernel(
    const float* __restrict__ xyz, const int* __restrict__ nidx,
    const float* __restrict__ Wp1, const float* __restrict__ bnp1,
    const float* __restrict__ Wp2, const float* __restrict__ bp2,
    const float* __restrict__ bnw0,
    const float* __restrict__ Ww1, const float* __restrict__ bnw1,
    const float* __restrict__ Ww2, const float* __restrict__ bw2,
    const float* __restrict__ bn_mid,
    const float* __restrict__ W2, const float* __restrict__ bn2,
    const float* __restrict__ f_ws, const float* __restrict__ q_ws,
    const unsigned short* __restrict__ kv_ws,
    float* __restrict__ out)
{
    __shared__ unsigned lww1h[8*32];   // Ww1 bf16-packed
    __shared__ float lw2[64*68];       // W2 rows stride 68 (conflict-free interleaved reads)
    __shared__ float lout[64*33];      // output transpose: [channel][point], stride 33
    const int t = threadIdx.x;
    if (t < 256){
        const int j = t>>5, c2 = t&31;
        lww1h[j*32+c2] = pk2(Ww1[j*64+2*c2], Ww1[j*64+2*c2+1]);
    }
#pragma unroll
    for (int r=0;r<16;++r){
        const int idx = t + r*256;
        const int o = idx>>6, c = idx&63;
        lw2[o*68+c] = W2[idx];
    }
    __syncthreads();

    // identity block order (remap removed — batch-clustered dispatch keeps each
    // batch's 4MB kv footprint hot in L2 across all XCDs)
    const int tid = blockIdx.x*256 + t;
    const int ll  = t & 7;
    const int p   = tid >> 3;
    const int b   = p >> 14;
    const int obase = (t & 63) & 56;

    float wp1[9];
#pragma unroll
    for (int u=0;u<9;++u) wp1[u] = rfl(Wp1[u]);
    float sp1[3], tp1[3];
#pragma unroll
    for (int o=0;o<3;++o){
        const float s = bnp1[o]*rsqrtf(bnp1[9+o]+EPSV);
        sp1[o]=rfl(s); tp1[o]=rfl(fmaf(-bnp1[6+o], s, bnp1[3+o]));
    }
    float sw1[8], tw1[8];
#pragma unroll
    for (int j=0;j<8;++j){
        const float s = bnw1[j]*rsqrtf(bnw1[24+j]+EPSV);
        sw1[j]=rfl(s); tw1[j]=rfl(fmaf(-bnw1[16+j], s, bnw1[8+j]));
    }
    float wp2f[24];
#pragma unroll
    for (int u=0;u<6;++u){
        const float4 w = ((const float4*)Wp2)[6*ll+u];
        wp2f[4*u]=w.x; wp2f[4*u+1]=w.y; wp2f[4*u+2]=w.z; wp2f[4*u+3]=w.w;
    }
    float ww2r[8]; float bwr;
    {
        const float4 a = ((const float4*)Ww2)[2*ll], c = ((const float4*)Ww2)[2*ll+1];
        ww2r[0]=a.x; ww2r[1]=a.y; ww2r[2]=a.z; ww2r[3]=a.w;
        ww2r[4]=c.x; ww2r[5]=c.y; ww2r[6]=c.z; ww2r[7]=c.w;
        bwr = bw2[ll];
    }
    float s0[8], qc[8], bpv[8];
    {
        float qv[8];
        const float4* qp = (const float4*)(q_ws + p*64 + 8*ll);
        const float4 q0 = qp[0], q1 = qp[1];
        qv[0]=q0.x;qv[1]=q0.y;qv[2]=q0.z;qv[3]=q0.w; qv[4]=q1.x;qv[5]=q1.y;qv[6]=q1.z;qv[7]=q1.w;
        const float4* bp = (const float4*)(bp2 + 8*ll);
        const float4 b0 = bp[0], b1 = bp[1];
        bpv[0]=b0.x;bpv[1]=b0.y;bpv[2]=b0.z;bpv[3]=b0.w; bpv[4]=b1.x;bpv[5]=b1.y;bpv[6]=b1.z;bpv[7]=b1.w;
        const float4* g4 = (const float4*)(bnw0 + 8*ll);
        const float4 g0=g4[0], g1=g4[1];
        const float4* be4 = (const float4*)(bnw0 + 64 + 8*ll);
        const float4 e0=be4[0], e1=be4[1];
        const float4* m4 = (const float4*)(bnw0 + 128 + 8*ll);
        const float4 m0=m4[0], m1=m4[1];
        const float4* v4 = (const float4*)(bnw0 + 192 + 8*ll);
        const float4 v0=v4[0], v1=v4[1];
        const float gg[8]={g0.x,g0.y,g0.z,g0.w,g1.x,g1.y,g1.z,g1.w};
        const float bb[8]={e0.x,e0.y,e0.z,e0.w,e1.x,e1.y,e1.z,e1.w};
        const float mm[8]={m0.x,m0.y,m0.z,m0.w,m1.x,m1.y,m1.z,m1.w};
        const float vv[8]={v0.x,v0.y,v0.z,v0.w,v1.x,v1.y,v1.z,v1.w};
#pragma unroll
        for (int i=0;i<8;++i){
            const float s = gg[i]*rsqrtf(vv[i]+EPSV);
            s0[i]=s;
            qc[i]=fmaf(-mm[i], s, bb[i]) + s*(bpv[i]-qv[i]);
        }
    }

    float m[8], l[8], acc[8];
#pragma unroll
    for (int j=0;j<8;++j){ m[j]=-3.0e38f; l[j]=0.f; acc[j]=0.f; }

    const int* nip = nidx + p*16;

#pragma unroll 2
    for (int k=0;k<KNBR;++k){
        const int ni   = nip[k];
        const int rowb = (b<<14) + ni;
        const uint4* kvp = (const uint4*)(kv_ws + (size_t)rowb*128);
        const uint4 ku = kvp[ll];
        const uint4 vu = kvp[8+ll];
        const float* xp = xyz + rowb*3;
        const float x0=xp[0], x1=xp[1], x2v=xp[2];

        float t3[3];
#pragma unroll
        for (int o=0;o<3;++o){
            const float u = fmaf(wp1[3*o], x0, fmaf(wp1[3*o+1], x1, wp1[3*o+2]*x2v));
            t3[o] = fmaxf(fmaf(u, sp1[o], tp1[o]), 0.f);
        }
        float kf[8];
        unpk(ku.x, kf[0], kf[1]); unpk(ku.y, kf[2], kf[3]);
        unpk(ku.z, kf[4], kf[5]); unpk(ku.w, kf[6], kf[7]);
        float pr[8], wl[8];
#pragma unroll
        for (int i=0;i<8;++i){
            pr[i] = fmaf(wp2f[3*i], t3[0], fmaf(wp2f[3*i+1], t3[1], wp2f[3*i+2]*t3[2]));
            wl[i] = lrelu_(fmaf(s0[i], kf[i]+pr[i], qc[i]));
        }
        float y[8];
#pragma unroll
        for (int j=0;j<8;++j){
            const uint4 w = *(const uint4*)(lww1h + j*32 + 4*ll);
            float a,c, yy;
            unpk(w.x,a,c); yy  = a*wl[0];        yy = fmaf(c,wl[1],yy);
            unpk(w.y,a,c); yy = fmaf(a,wl[2],yy); yy = fmaf(c,wl[3],yy);
            unpk(w.z,a,c); yy = fmaf(a,wl[4],yy); yy = fmaf(c,wl[5],yy);
            unpk(w.w,a,c); yy = fmaf(a,wl[6],yy); yy = fmaf(c,wl[7],yy);
            yy += __shfl_xor(yy, 1);
            yy += __shfl_xor(yy, 2);
            yy += __shfl_xor(yy, 4);
            y[j] = yy;
        }
#pragma unroll
        for (int j=0;j<8;++j) y[j] = fmaxf(fmaf(y[j], sw1[j], tw1[j]), 0.f);
        float w2own = bwr;
#pragma unroll
        for (int j=0;j<8;++j) w2own = fmaf(ww2r[j], y[j], w2own);
        float w2[8];
        w2[0]=__shfl(w2own, obase+0); w2[1]=__shfl(w2own, obase+1);
        w2[2]=__shfl(w2own, obase+2); w2[3]=__shfl(w2own, obase+3);
        w2[4]=__shfl(w2own, obase+4); w2[5]=__shfl(w2own, obase+5);
        w2[6]=__shfl(w2own, obase+6); w2[7]=__shfl(w2own, obase+7);

        float sc[8], e[8];
#pragma unroll
        for (int j=0;j<8;++j){
            const float mn = fmaxf(m[j], w2[j]);
            sc[j] = __expf(m[j]-mn);
            e[j]  = __expf(w2[j]-mn);
            l[j]  = fmaf(l[j], sc[j], e[j]);
            m[j]  = mn;
        }
        float vf[8];
        unpk(vu.x, vf[0], vf[1]); unpk(vu.y, vf[2], vf[3]);
        unpk(vu.z, vf[4], vf[5]); unpk(vu.w, vf[6], vf[7]);
#pragma unroll
        for (int i=0;i<8;++i)
            acc[i] = fmaf(acc[i], sc[i], (vf[i]+pr[i])*e[i]);
    }

    // normalize + deferred bp2 + bn_mid + lrelu
    float xm[8];
    {
        const float4* g4 = (const float4*)(bn_mid + 8*ll);
        const float4 g0=g4[0], g1=g4[1];
        const float4* be4 = (const float4*)(bn_mid + 64 + 8*ll);
        const float4 e0=be4[0], e1=be4[1];
        const float4* m4 = (const float4*)(bn_mid + 128 + 8*ll);
        const float4 m0=m4[0], m1=m4[1];
        const float4* v4 = (const float4*)(bn_mid + 192 + 8*ll);
        const float4 v0=v4[0], v1=v4[1];
        const float gg[8]={g0.x,g0.y,g0.z,g0.w,g1.x,g1.y,g1.z,g1.w};
        const float bb[8]={e0.x,e0.y,e0.z,e0.w,e1.x,e1.y,e1.z,e1.w};
        const float mm[8]={m0.x,m0.y,m0.z,m0.w,m1.x,m1.y,m1.z,m1.w};
        const float vv[8]={v0.x,v0.y,v0.z,v0.w,v1.x,v1.y,v1.z,v1.w};
#pragma unroll
        for (int i=0;i<8;++i){
            const float s = gg[i]*rsqrtf(vv[i]+EPSV);
            const float tt = fmaf(-mm[i], s, bb[i]);
            const float xx = fmaf(acc[i], 1.f/l[i], bpv[i]);
            xm[i] = lrelu_(fmaf(xx, s, tt));
        }
    }
    float Zx0[4],Zx1[4],Zx2[4],Zx3[4],Zx4[4],Zx5[4],Zx6[4],Zx7[4];
    float Zx8[4],Zx9[4],Zx10[4],Zx11[4],Zx12[4],Zx13[4],Zx14[4],Zx15[4];
#pragma unroll
    for (int r=0;r<4;++r){
        Zx0[r] =__shfl(xm[r],   obase+0); Zx1[r] =__shfl(xm[4+r], obase+0);
        Zx2[r] =__shfl(xm[r],   obase+1); Zx3[r] =__shfl(xm[4+r], obase+1);
        Zx4[r] =__shfl(xm[r],   obase+2); Zx5[r] =__shfl(xm[4+r], obase+2);
        Zx6[r] =__shfl(xm[r],   obase+3); Zx7[r] =__shfl(xm[4+r], obase+3);
        Zx8[r] =__shfl(xm[r],   obase+4); Zx9[r] =__shfl(xm[4+r], obase+4);
        Zx10[r]=__shfl(xm[r],   obase+5); Zx11[r]=__shfl(xm[4+r], obase+5);
        Zx12[r]=__shfl(xm[r],   obase+6); Zx13[r]=__shfl(xm[4+r], obase+6);
        Zx14[r]=__shfl(xm[r],   obase+7); Zx15[r]=__shfl(xm[4+r], obase+7);
    }
#define DOT4(W4, Z) (fmaf((W4).w, (Z)[3], fmaf((W4).z, (Z)[2], fmaf((W4).y, (Z)[1], (W4).x*(Z)[0]))))
    const float* fpw = f_ws + p*64;
    const int pidx = t >> 3;                 // point index within block (0..31)
#pragma unroll
    for (int i=0;i<8;++i){
        const int o = 8*i+ll;
        const float4* row = (const float4*)(lw2 + o*68);
        float hs = 0.f;
        hs += DOT4(row[0],  Zx0);  hs += DOT4(row[1],  Zx1);
        hs += DOT4(row[2],  Zx2);  hs += DOT4(row[3],  Zx3);
        hs += DOT4(row[4],  Zx4);  hs += DOT4(row[5],  Zx5);
        hs += DOT4(row[6],  Zx6);  hs += DOT4(row[7],  Zx7);
        hs += DOT4(row[8],  Zx8);  hs += DOT4(row[9],  Zx9);
        hs += DOT4(row[10], Zx10); hs += DOT4(row[11], Zx11);
        hs += DOT4(row[12], Zx12); hs += DOT4(row[13], Zx13);
        hs += DOT4(row[14], Zx14); hs += DOT4(row[15], Zx15);
        const float s2 = bn2[o]*rsqrtf(bn2[192+o]+EPSV);
        const float t2 = fmaf(-bn2[128+o], s2, bn2[64+o]);
        const float x2r = fmaf(hs, s2, t2);
        lout[o*33 + pidx] = lrelu_(fpw[o] + x2r);
    }
#undef DOT4
    __syncthreads();
    // coalesced store: thread t -> channel t>>2, points (t&3)*8 .. +7 (two dwordx4)
    {
        const int oc = t >> 2;
        const int j0 = (t & 3) * 8;
        const int p0 = blockIdx.x * 32;          // block's first point
        const int bb = p0 >> 14;
        const int n0 = p0 & (NPTS-1);
        float v0[4], v1[4];
#pragma unroll
        for (int r=0;r<4;++r){ v0[r] = lout[oc*33 + j0 + r]; v1[r] = lout[oc*33 + j0 + 4 + r]; }
        float* op = out + (size_t)(bb*64 + oc)*NPTS + n0 + j0;
        ((float4*)op)[0] = make_float4(v0[0],v0[1],v0[2],v0[3]);
        ((float4*)op)[1] = make_float4(v1[0],v1[1],v1[2],v1[3]);
    }
}

extern "C" void kernel_launch(void* const* d_in, const int* in_sizes, int n_in,
                              void* d_out, int out_size, void* d_ws, size_t ws_size,
                              hipStream_t stream) {
    const float* feature = (const float*)d_in[0];
    const float* xyz     = (const float*)d_in[1];
    const float* W1      = (const float*)d_in[2];
    const float* bn1     = (const float*)d_in[3];
    const float* Wq      = (const float*)d_in[4];
    const float* bq      = (const float*)d_in[5];
    const float* Wk      = (const float*)d_in[6];
    const float* bk      = (const float*)d_in[7];
    const float* Wv      = (const float*)d_in[8];
    const float* bv      = (const float*)d_in[9];
    const float* Wp1     = (const float*)d_in[10];
    const float* bnp1    = (const float*)d_in[11];
    const float* Wp2     = (const float*)d_in[12];
    const float* bp2     = (const float*)d_in[13];
    const float* bnw0    = (const float*)d_in[14];
    const float* Ww1     = (const float*)d_in[15];
    const float* bnw1    = (const float*)d_in[16];
    const float* Ww2     = (const float*)d_in[17];
    const float* bw2     = (const float*)d_in[18];
    const float* bn_mid  = (const float*)d_in[19];
    const float* W2      = (const float*)d_in[20];
    const float* bn2     = (const float*)d_in[21];
    const int*   nidx    = (const int*)d_in[22];
    float* out = (float*)d_out;

    // ws: f (8MB fp32) | q (8MB fp32) | kv (8MB bf16 packed, k||v per point)
    float* ws   = (float*)d_ws;
    float* f_ws = ws;
    float* q_ws = ws + 2097152;
    unsigned short* kv_ws = (unsigned short*)(ws + 4194304);

    qkvf_kernel<<<1024, 256, 0, stream>>>(feature, W1, bn1, Wq, bq, Wk, bk, Wv, bv,
                                          f_ws, q_ws, kv_ws);
    attn_kernel<<<1024, 256, 0, stream>>>(xyz, nidx, Wp1, bnp1, Wp2, bp2, bnw0,
                                          Ww1, bnw1, Ww2, bw2, bn_mid, W2, bn2,
                                          f_ws, q_ws, kv_ws, out);
}

// Round 7
// 183.608 us; speedup vs baseline: 1.8561x; 1.8459x over previous
//
#include <hip/hip_runtime.h>
#include <hip/hip_bf16.h>
#include <math.h>

#define NPTS 16384
#define KNBR 16
#define EPSV 1e-5f

__device__ __forceinline__ float lrelu_(float x){ return fmaxf(x, 0.2f*x); }
__device__ __forceinline__ float rfl(float x){
    return __uint_as_float((unsigned)__builtin_amdgcn_readfirstlane(__float_as_uint(x)));
}
__device__ __forceinline__ unsigned pk2(float lo, float hi){
    __hip_bfloat16 a = __float2bfloat16(lo), b = __float2bfloat16(hi);
    unsigned short ua = *reinterpret_cast<unsigned short*>(&a);
    unsigned short ub = *reinterpret_cast<unsigned short*>(&b);
    return (unsigned)ua | ((unsigned)ub << 16);
}
__device__ __forceinline__ unsigned short f2bs(float x){
    __hip_bfloat16 a = __float2bfloat16(x);
    return *reinterpret_cast<unsigned short*>(&a);
}
__device__ __forceinline__ void unpk(unsigned u, float& lo, float& hi){
    lo = __uint_as_float(u << 16);
    hi = __uint_as_float(u & 0xffff0000u);
}

// ---------------- Kernel 1: f/q/k/v. 8 lanes/point, bf16 weights in LDS (~33KB). ----------------
__global__ __launch_bounds__(256,3) void qkvf_kernel(
    const float* __restrict__ feature,
    const float* __restrict__ W1, const float* __restrict__ bn1,
    const float* __restrict__ Wq, const float* __restrict__ bq,
    const float* __restrict__ Wk, const float* __restrict__ bk,
    const float* __restrict__ Wv, const float* __restrict__ bv,
    float* __restrict__ f_ws, float* __restrict__ q_ws,
    unsigned short* __restrict__ kv_ws)
{
    __shared__ unsigned lw1h[64*20];
    __shared__ unsigned lwqh[64*36];
    __shared__ unsigned lwkh[64*36];
    __shared__ unsigned lwvh[64*36];
    __shared__ float lbq[64], lbk[64], lbv[64], ls1[64], lt1[64];

    const int t = threadIdx.x;
#pragma unroll
    for (int r=0;r<4;++r){
        const int idx = t + r*256;                 // 0..1023
        const int o = idx>>4, c2 = idx&15;
        lw1h[o*20+c2] = pk2(W1[o*32+2*c2], W1[o*32+2*c2+1]);
    }
#pragma unroll
    for (int r=0;r<8;++r){
        const int idx = t + r*256;                 // 0..2047
        const int o = idx>>5, c2 = idx&31;
        lwqh[o*36+c2] = pk2(Wq[o*64+2*c2], Wq[o*64+2*c2+1]);
        lwkh[o*36+c2] = pk2(Wk[o*64+2*c2], Wk[o*64+2*c2+1]);
        lwvh[o*36+c2] = pk2(Wv[o*64+2*c2], Wv[o*64+2*c2+1]);
    }
    if (t<64){
        lbq[t]=bq[t]; lbk[t]=bk[t]; lbv[t]=bv[t];
        const float s = bn1[t]*rsqrtf(bn1[192+t]+EPSV);
        ls1[t]=s; lt1[t]=fmaf(-bn1[128+t], s, bn1[64+t]);
    }
    __syncthreads();

    const int tid   = blockIdx.x*256 + t;          // 0 .. B*N*8-1
    const int ll    = t & 7;
    const int p     = tid >> 3;
    const int b     = p >> 14;
    const int n     = p & (NPTS-1);
    const int obase = (t & 63) & 56;

    float ft[4];
    const float* fbase = feature + b*32*NPTS + n;
#pragma unroll
    for (int u=0;u<4;++u) ft[u] = fbase[(8*u+ll)*NPTS];

    float Yf0[4],Yf1[4],Yf2[4],Yf3[4],Yf4[4],Yf5[4],Yf6[4],Yf7[4];
#pragma unroll
    for (int u=0;u<4;++u){
        Yf0[u]=__shfl(ft[u], obase+0); Yf1[u]=__shfl(ft[u], obase+1);
        Yf2[u]=__shfl(ft[u], obase+2); Yf3[u]=__shfl(ft[u], obase+3);
        Yf4[u]=__shfl(ft[u], obase+4); Yf5[u]=__shfl(ft[u], obase+5);
        Yf6[u]=__shfl(ft[u], obase+6); Yf7[u]=__shfl(ft[u], obase+7);
    }

    float fv[8];
#pragma unroll
    for (int i=0;i<8;++i){
        const int o = 8*i+ll;
        const uint4* row = (const uint4*)(lw1h + o*20);
        float hs = 0.f;
#pragma unroll
        for (int g=0;g<4;++g){
            const uint4 w = row[g];
            float a,c;
            unpk(w.x,a,c); hs=fmaf(a,Yf0[g],hs); hs=fmaf(c,Yf1[g],hs);
            unpk(w.y,a,c); hs=fmaf(a,Yf2[g],hs); hs=fmaf(c,Yf3[g],hs);
            unpk(w.z,a,c); hs=fmaf(a,Yf4[g],hs); hs=fmaf(c,Yf5[g],hs);
            unpk(w.w,a,c); hs=fmaf(a,Yf6[g],hs); hs=fmaf(c,Yf7[g],hs);
        }
        fv[i] = fmaxf(fmaf(hs, ls1[o], lt1[o]), 0.f);
        f_ws[p*64+o] = fv[i];
    }

    float Y0[8],Y1[8],Y2[8],Y3[8],Y4[8],Y5[8],Y6[8],Y7[8];
#pragma unroll
    for (int u=0;u<8;++u){
        Y0[u]=__shfl(fv[u], obase+0); Y1[u]=__shfl(fv[u], obase+1);
        Y2[u]=__shfl(fv[u], obase+2); Y3[u]=__shfl(fv[u], obase+3);
        Y4[u]=__shfl(fv[u], obase+4); Y5[u]=__shfl(fv[u], obase+5);
        Y6[u]=__shfl(fv[u], obase+6); Y7[u]=__shfl(fv[u], obase+7);
    }

#define QKV_ROWS(LWH, LBIAS, STORE_STMT)                              \
    _Pragma("unroll")                                                 \
    for (int i=0;i<8;++i){                                            \
        const int o = 8*i+ll;                                         \
        const uint4* row = (const uint4*)(LWH + o*36);                \
        float hs = LBIAS[o];                                          \
        _Pragma("unroll")                                             \
        for (int g=0;g<8;++g){                                        \
            const uint4 w = row[g];                                   \
            float a,c;                                                \
            unpk(w.x,a,c); hs=fmaf(a,Y0[g],hs); hs=fmaf(c,Y1[g],hs);  \
            unpk(w.y,a,c); hs=fmaf(a,Y2[g],hs); hs=fmaf(c,Y3[g],hs);  \
            unpk(w.z,a,c); hs=fmaf(a,Y4[g],hs); hs=fmaf(c,Y5[g],hs);  \
            unpk(w.w,a,c); hs=fmaf(a,Y6[g],hs); hs=fmaf(c,Y7[g],hs);  \
        }                                                             \
        STORE_STMT;                                                   \
    }

    QKV_ROWS(lwqh, lbq, q_ws[p*64+o] = hs)
    QKV_ROWS(lwkh, lbk, kv_ws[p*128+o] = f2bs(hs))
    QKV_ROWS(lwvh, lbv, kv_ws[p*128+64+o] = f2bs(hs))
#undef QKV_ROWS
}

// ---------------- Kernel 2: gather + attention + epilogue. 8 lanes/point. ----------------
// NOTE: no min-waves launch bound — Round 5/6's (256,3) capped VGPRs (~168) below the
// k-loop live set and forced scratch spill (~190MB extra FETCH + ~186MB extra WRITE).
__global__ __launch_bounds__(256) void attn_kernel(
    const float* __restrict__ xyz, const int* __restrict__ nidx,
    const float* __restrict__ Wp1, const float* __restrict__ bnp1,
    const float* __restrict__ Wp2, const float* __restrict__ bp2,
    const float* __restrict__ bnw0,
    const float* __restrict__ Ww1, const float* __restrict__ bnw1,
    const float* __restrict__ Ww2, const float* __restrict__ bw2,
    const float* __restrict__ bn_mid,
    const float* __restrict__ W2, const float* __restrict__ bn2,
    const float* __restrict__ f_ws, const float* __restrict__ q_ws,
    const unsigned short* __restrict__ kv_ws,
    float* __restrict__ out)
{
    __shared__ unsigned lww1h[8*32];   // Ww1 bf16-packed
    __shared__ float lw2[64*68];       // W2 rows stride 68 (conflict-free interleaved reads)
    __shared__ float lout[64*33];      // output transpose: [channel][point], stride 33
    const int t = threadIdx.x;
    if (t < 256){
        const int j = t>>5, c2 = t&31;
        lww1h[j*32+c2] = pk2(Ww1[j*64+2*c2], Ww1[j*64+2*c2+1]);
    }
#pragma unroll
    for (int r=0;r<16;++r){
        const int idx = t + r*256;
        const int o = idx>>6, c = idx&63;
        lw2[o*68+c] = W2[idx];
    }
    __syncthreads();

    const int tid = blockIdx.x*256 + t;
    const int ll  = t & 7;
    const int p   = tid >> 3;
    const int b   = p >> 14;
    const int obase = (t & 63) & 56;

    float wp1[9];
#pragma unroll
    for (int u=0;u<9;++u) wp1[u] = rfl(Wp1[u]);
    float sp1[3], tp1[3];
#pragma unroll
    for (int o=0;o<3;++o){
        const float s = bnp1[o]*rsqrtf(bnp1[9+o]+EPSV);
        sp1[o]=rfl(s); tp1[o]=rfl(fmaf(-bnp1[6+o], s, bnp1[3+o]));
    }
    float sw1[8], tw1[8];
#pragma unroll
    for (int j=0;j<8;++j){
        const float s = bnw1[j]*rsqrtf(bnw1[24+j]+EPSV);
        sw1[j]=rfl(s); tw1[j]=rfl(fmaf(-bnw1[16+j], s, bnw1[8+j]));
    }
    float wp2f[24];
#pragma unroll
    for (int u=0;u<6;++u){
        const float4 w = ((const float4*)Wp2)[6*ll+u];
        wp2f[4*u]=w.x; wp2f[4*u+1]=w.y; wp2f[4*u+2]=w.z; wp2f[4*u+3]=w.w;
    }
    float ww2r[8]; float bwr;
    {
        const float4 a = ((const float4*)Ww2)[2*ll], c = ((const float4*)Ww2)[2*ll+1];
        ww2r[0]=a.x; ww2r[1]=a.y; ww2r[2]=a.z; ww2r[3]=a.w;
        ww2r[4]=c.x; ww2r[5]=c.y; ww2r[6]=c.z; ww2r[7]=c.w;
        bwr = bw2[ll];
    }
    // fold bnw0 + q + bp2 into qc (bpv NOT kept live across the loop — reloaded in epilogue)
    float s0[8], qc[8];
    {
        float qv[8], bpv[8];
        const float4* qp = (const float4*)(q_ws + p*64 + 8*ll);
        const float4 q0 = qp[0], q1 = qp[1];
        qv[0]=q0.x;qv[1]=q0.y;qv[2]=q0.z;qv[3]=q0.w; qv[4]=q1.x;qv[5]=q1.y;qv[6]=q1.z;qv[7]=q1.w;
        const float4* bp = (const float4*)(bp2 + 8*ll);
        const float4 b0 = bp[0], b1 = bp[1];
        bpv[0]=b0.x;bpv[1]=b0.y;bpv[2]=b0.z;bpv[3]=b0.w; bpv[4]=b1.x;bpv[5]=b1.y;bpv[6]=b1.z;bpv[7]=b1.w;
        const float4* g4 = (const float4*)(bnw0 + 8*ll);
        const float4 g0=g4[0], g1=g4[1];
        const float4* be4 = (const float4*)(bnw0 + 64 + 8*ll);
        const float4 e0=be4[0], e1=be4[1];
        const float4* m4 = (const float4*)(bnw0 + 128 + 8*ll);
        const float4 m0=m4[0], m1=m4[1];
        const float4* v4 = (const float4*)(bnw0 + 192 + 8*ll);
        const float4 v0=v4[0], v1=v4[1];
        const float gg[8]={g0.x,g0.y,g0.z,g0.w,g1.x,g1.y,g1.z,g1.w};
        const float bb[8]={e0.x,e0.y,e0.z,e0.w,e1.x,e1.y,e1.z,e1.w};
        const float mm[8]={m0.x,m0.y,m0.z,m0.w,m1.x,m1.y,m1.z,m1.w};
        const float vv[8]={v0.x,v0.y,v0.z,v0.w,v1.x,v1.y,v1.z,v1.w};
#pragma unroll
        for (int i=0;i<8;++i){
            const float s = gg[i]*rsqrtf(vv[i]+EPSV);
            s0[i]=s;
            qc[i]=fmaf(-mm[i], s, bb[i]) + s*(bpv[i]-qv[i]);
        }
    }

    float m[8], l[8], acc[8];
#pragma unroll
    for (int j=0;j<8;++j){ m[j]=-3.0e38f; l[j]=0.f; acc[j]=0.f; }

    const int* nip = nidx + p*16;

#pragma unroll 2
    for (int k=0;k<KNBR;++k){
        const int ni   = nip[k];
        const int rowb = (b<<14) + ni;
        const uint4* kvp = (const uint4*)(kv_ws + (size_t)rowb*128);
        const uint4 ku = kvp[ll];
        const uint4 vu = kvp[8+ll];
        const float* xp = xyz + rowb*3;
        const float x0=xp[0], x1=xp[1], x2v=xp[2];

        float t3[3];
#pragma unroll
        for (int o=0;o<3;++o){
            const float u = fmaf(wp1[3*o], x0, fmaf(wp1[3*o+1], x1, wp1[3*o+2]*x2v));
            t3[o] = fmaxf(fmaf(u, sp1[o], tp1[o]), 0.f);
        }
        float kf[8];
        unpk(ku.x, kf[0], kf[1]); unpk(ku.y, kf[2], kf[3]);
        unpk(ku.z, kf[4], kf[5]); unpk(ku.w, kf[6], kf[7]);
        float pr[8], wl[8];
#pragma unroll
        for (int i=0;i<8;++i){
            pr[i] = fmaf(wp2f[3*i], t3[0], fmaf(wp2f[3*i+1], t3[1], wp2f[3*i+2]*t3[2]));
            wl[i] = lrelu_(fmaf(s0[i], kf[i]+pr[i], qc[i]));
        }
        float y[8];
#pragma unroll
        for (int j=0;j<8;++j){
            const uint4 w = *(const uint4*)(lww1h + j*32 + 4*ll);
            float a,c, yy;
            unpk(w.x,a,c); yy  = a*wl[0];        yy = fmaf(c,wl[1],yy);
            unpk(w.y,a,c); yy = fmaf(a,wl[2],yy); yy = fmaf(c,wl[3],yy);
            unpk(w.z,a,c); yy = fmaf(a,wl[4],yy); yy = fmaf(c,wl[5],yy);
            unpk(w.w,a,c); yy = fmaf(a,wl[6],yy); yy = fmaf(c,wl[7],yy);
            yy += __shfl_xor(yy, 1);
            yy += __shfl_xor(yy, 2);
            yy += __shfl_xor(yy, 4);
            y[j] = yy;
        }
#pragma unroll
        for (int j=0;j<8;++j) y[j] = fmaxf(fmaf(y[j], sw1[j], tw1[j]), 0.f);
        float w2own = bwr;
#pragma unroll
        for (int j=0;j<8;++j) w2own = fmaf(ww2r[j], y[j], w2own);
        float w2[8];
        w2[0]=__shfl(w2own, obase+0); w2[1]=__shfl(w2own, obase+1);
        w2[2]=__shfl(w2own, obase+2); w2[3]=__shfl(w2own, obase+3);
        w2[4]=__shfl(w2own, obase+4); w2[5]=__shfl(w2own, obase+5);
        w2[6]=__shfl(w2own, obase+6); w2[7]=__shfl(w2own, obase+7);

        float sc[8], e[8];
#pragma unroll
        for (int j=0;j<8;++j){
            const float mn = fmaxf(m[j], w2[j]);
            sc[j] = __expf(m[j]-mn);
            e[j]  = __expf(w2[j]-mn);
            l[j]  = fmaf(l[j], sc[j], e[j]);
            m[j]  = mn;
        }
        float vf[8];
        unpk(vu.x, vf[0], vf[1]); unpk(vu.y, vf[2], vf[3]);
        unpk(vu.z, vf[4], vf[5]); unpk(vu.w, vf[6], vf[7]);
#pragma unroll
        for (int i=0;i<8;++i)
            acc[i] = fmaf(acc[i], sc[i], (vf[i]+pr[i])*e[i]);
    }

    // normalize + deferred bp2 + bn_mid + lrelu (bp2 reloaded here, L1-hot)
    float xm[8];
    {
        const float4* bp = (const float4*)(bp2 + 8*ll);
        const float4 b0 = bp[0], b1 = bp[1];
        const float bpv[8]={b0.x,b0.y,b0.z,b0.w,b1.x,b1.y,b1.z,b1.w};
        const float4* g4 = (const float4*)(bn_mid + 8*ll);
        const float4 g0=g4[0], g1=g4[1];
        const float4* be4 = (const float4*)(bn_mid + 64 + 8*ll);
        const float4 e0=be4[0], e1=be4[1];
        const float4* m4 = (const float4*)(bn_mid + 128 + 8*ll);
        const float4 m0=m4[0], m1=m4[1];
        const float4* v4 = (const float4*)(bn_mid + 192 + 8*ll);
        const float4 v0=v4[0], v1=v4[1];
        const float gg[8]={g0.x,g0.y,g0.z,g0.w,g1.x,g1.y,g1.z,g1.w};
        const float bb[8]={e0.x,e0.y,e0.z,e0.w,e1.x,e1.y,e1.z,e1.w};
        const float mm[8]={m0.x,m0.y,m0.z,m0.w,m1.x,m1.y,m1.z,m1.w};
        const float vv[8]={v0.x,v0.y,v0.z,v0.w,v1.x,v1.y,v1.z,v1.w};
#pragma unroll
        for (int i=0;i<8;++i){
            const float s = gg[i]*rsqrtf(vv[i]+EPSV);
            const float tt = fmaf(-mm[i], s, bb[i]);
            const float xx = fmaf(acc[i], 1.f/l[i], bpv[i]);
            xm[i] = lrelu_(fmaf(xx, s, tt));
        }
    }
    float Zx0[4],Zx1[4],Zx2[4],Zx3[4],Zx4[4],Zx5[4],Zx6[4],Zx7[4];
    float Zx8[4],Zx9[4],Zx10[4],Zx11[4],Zx12[4],Zx13[4],Zx14[4],Zx15[4];
#pragma unroll
    for (int r=0;r<4;++r){
        Zx0[r] =__shfl(xm[r],   obase+0); Zx1[r] =__shfl(xm[4+r], obase+0);
        Zx2[r] =__shfl(xm[r],   obase+1); Zx3[r] =__shfl(xm[4+r], obase+1);
        Zx4[r] =__shfl(xm[r],   obase+2); Zx5[r] =__shfl(xm[4+r], obase+2);
        Zx6[r] =__shfl(xm[r],   obase+3); Zx7[r] =__shfl(xm[4+r], obase+3);
        Zx8[r] =__shfl(xm[r],   obase+4); Zx9[r] =__shfl(xm[4+r], obase+4);
        Zx10[r]=__shfl(xm[r],   obase+5); Zx11[r]=__shfl(xm[4+r], obase+5);
        Zx12[r]=__shfl(xm[r],   obase+6); Zx13[r]=__shfl(xm[4+r], obase+6);
        Zx14[r]=__shfl(xm[r],   obase+7); Zx15[r]=__shfl(xm[4+r], obase+7);
    }
#define DOT4(W4, Z) (fmaf((W4).w, (Z)[3], fmaf((W4).z, (Z)[2], fmaf((W4).y, (Z)[1], (W4).x*(Z)[0]))))
    const float* fpw = f_ws + p*64;
    const int pidx = t >> 3;                 // point index within block (0..31)
#pragma unroll
    for (int i=0;i<8;++i){
        const int o = 8*i+ll;
        const float4* row = (const float4*)(lw2 + o*68);
        float hs = 0.f;
        hs += DOT4(row[0],  Zx0);  hs += DOT4(row[1],  Zx1);
        hs += DOT4(row[2],  Zx2);  hs += DOT4(row[3],  Zx3);
        hs += DOT4(row[4],  Zx4);  hs += DOT4(row[5],  Zx5);
        hs += DOT4(row[6],  Zx6);  hs += DOT4(row[7],  Zx7);
        hs += DOT4(row[8],  Zx8);  hs += DOT4(row[9],  Zx9);
        hs += DOT4(row[10], Zx10); hs += DOT4(row[11], Zx11);
        hs += DOT4(row[12], Zx12); hs += DOT4(row[13], Zx13);
        hs += DOT4(row[14], Zx14); hs += DOT4(row[15], Zx15);
        const float s2 = bn2[o]*rsqrtf(bn2[192+o]+EPSV);
        const float t2 = fmaf(-bn2[128+o], s2, bn2[64+o]);
        const float x2r = fmaf(hs, s2, t2);
        lout[o*33 + pidx] = lrelu_(fpw[o] + x2r);
    }
#undef DOT4
    __syncthreads();
    // coalesced store: thread t -> channel t>>2, points (t&3)*8 .. +7 (two dwordx4)
    {
        const int oc = t >> 2;
        const int j0 = (t & 3) * 8;
        const int p0 = blockIdx.x * 32;          // block's first point
        const int bb = p0 >> 14;
        const int n0 = p0 & (NPTS-1);
        float v0[4], v1[4];
#pragma unroll
        for (int r=0;r<4;++r){ v0[r] = lout[oc*33 + j0 + r]; v1[r] = lout[oc*33 + j0 + 4 + r]; }
        float* op = out + (size_t)(bb*64 + oc)*NPTS + n0 + j0;
        ((float4*)op)[0] = make_float4(v0[0],v0[1],v0[2],v0[3]);
        ((float4*)op)[1] = make_float4(v1[0],v1[1],v1[2],v1[3]);
    }
}

extern "C" void kernel_launch(void* const* d_in, const int* in_sizes, int n_in,
                              void* d_out, int out_size, void* d_ws, size_t ws_size,
                              hipStream_t stream) {
    const float* feature = (const float*)d_in[0];
    const float* xyz     = (const float*)d_in[1];
    const float* W1      = (const float*)d_in[2];
    const float* bn1     = (const float*)d_in[3];
    const float* Wq      = (const float*)d_in[4];
    const float* bq      = (const float*)d_in[5];
    const float* Wk      = (const float*)d_in[6];
    const float* bk      = (const float*)d_in[7];
    const float* Wv      = (const float*)d_in[8];
    const float* bv      = (const float*)d_in[9];
    const float* Wp1     = (const float*)d_in[10];
    const float* bnp1    = (const float*)d_in[11];
    const float* Wp2     = (const float*)d_in[12];
    const float* bp2     = (const float*)d_in[13];
    const float* bnw0    = (const float*)d_in[14];
    const float* Ww1     = (const float*)d_in[15];
    const float* bnw1    = (const float*)d_in[16];
    const float* Ww2     = (const float*)d_in[17];
    const float* bw2     = (const float*)d_in[18];
    const float* bn_mid  = (const float*)d_in[19];
    const float* W2      = (const float*)d_in[20];
    const float* bn2     = (const float*)d_in[21];
    const int*   nidx    = (const int*)d_in[22];
    float* out = (float*)d_out;

    // ws: f (8MB fp32) | q (8MB fp32) | kv (8MB bf16 packed, k||v per point)
    float* ws   = (float*)d_ws;
    float* f_ws = ws;
    float* q_ws = ws + 2097152;
    unsigned short* kv_ws = (unsigned short*)(ws + 4194304);

    qkvf_kernel<<<1024, 256, 0, stream>>>(feature, W1, bn1, Wq, bq, Wk, bk, Wv, bv,
                                          f_ws, q_ws, kv_ws);
    attn_kernel<<<1024, 256, 0, stream>>>(xyz, nidx, Wp1, bnp1, Wp2, bp2, bnw0,
                                          Ww1, bnw1, Ww2, bw2, bn_mid, W2, bn2,
                                          f_ws, q_ws, kv_ws, out);
}

// Round 11
// 167.584 us; speedup vs baseline: 2.0336x; 1.0956x over previous
//
#include <hip/hip_runtime.h>
#include <hip/hip_bf16.h>
#include <math.h>

#define NPTS 16384
#define KNBR 16
#define EPSV 1e-5f

typedef __attribute__((ext_vector_type(8))) short bf16x8;
typedef __attribute__((ext_vector_type(4))) float f32x4;

__device__ __forceinline__ float lrelu_(float x){ return fmaxf(x, 0.2f*x); }
__device__ __forceinline__ float rfl(float x){
    return __uint_as_float((unsigned)__builtin_amdgcn_readfirstlane(__float_as_uint(x)));
}
__device__ __forceinline__ unsigned pk2(float lo, float hi){
    __hip_bfloat16 a = __float2bfloat16(lo), b = __float2bfloat16(hi);
    unsigned short ua = *reinterpret_cast<unsigned short*>(&a);
    unsigned short ub = *reinterpret_cast<unsigned short*>(&b);
    return (unsigned)ua | ((unsigned)ub << 16);
}
__device__ __forceinline__ unsigned short f2bs(float x){
    __hip_bfloat16 a = __float2bfloat16(x);
    return *reinterpret_cast<unsigned short*>(&a);
}
__device__ __forceinline__ void unpk(unsigned u, float& lo, float& hi){
    lo = __uint_as_float(u << 16);
    hi = __uint_as_float(u & 0xffff0000u);
}
__device__ __forceinline__ bf16x8 mk8(float4 x, float4 y){
    union { unsigned u[4]; bf16x8 v; } z;
    z.u[0]=pk2(x.x,x.y); z.u[1]=pk2(x.z,x.w); z.u[2]=pk2(y.x,y.y); z.u[3]=pk2(y.z,y.w);
    return z.v;
}

// ---------------- Kernel 1: f/q/k/v via MFMA ----------------
// Block = 64 points. Wave w owns output rows [16w,16w+16).
// Fragment maps (mfma_f32_16x16x32_bf16): A[i][k]: i=lane&15, k=8*(lane>>4)+e;
// B[k][j]: j=lane&15, k=8*(lane>>4)+e; D[r][c]: c=lane&15, r=4*(lane>>4)+reg.
__global__ __launch_bounds__(256) void qkvf_kernel(
    const float* __restrict__ feature,
    const float* __restrict__ W1, const float* __restrict__ bn1,
    const float* __restrict__ Wq, const float* __restrict__ bq,
    const float* __restrict__ Wk, const float* __restrict__ bk,
    const float* __restrict__ Wv, const float* __restrict__ bv,
    unsigned* __restrict__ f_pk, unsigned* __restrict__ q_pk,
    unsigned* __restrict__ kv_u)
{
    __shared__ unsigned short lfeat[64*40];  // feat bf16 [pt][ch0..31], stride 40 shorts (80B)
    __shared__ unsigned lf[64*36];           // f bf16-pairs [pt][ch/2 0..31], stride 36 uints (144B)
    __shared__ unsigned lbuf[64*100];        // [pt][ q:0..31 | k:32..63 | v:64..95 ], stride 100

    const int t    = threadIdx.x;
    const int lane = t & 63;
    const int w    = t >> 6;                 // wave id 0..3
    const int i16  = lane & 15;
    const int g    = lane >> 4;              // k-group / row-group
    const int p0   = blockIdx.x * 64;
    const int b    = p0 >> 14;
    const int n0   = p0 & (NPTS-1);

    // ---- stage feature tile (bf16) ----
    {
        const float* fb = feature + b*32*NPTS + n0;
#pragma unroll
        for (int r=0;r<8;++r){
            const int idx = t + r*256;       // 0..2047
            const int ch = idx >> 6, pt = idx & 63;
            lfeat[pt*40 + ch] = f2bs(fb[ch*NPTS + pt]);
        }
    }

    // ---- A fragments (weights) in registers ----
    const int row = 16*w + i16;
    bf16x8 a1, aq0, aq1, ak0, ak1, av0, av1;
    {
        const float4* v4;
        v4 = (const float4*)(W1 + row*32 + 8*g);  a1  = mk8(v4[0], v4[1]);
        v4 = (const float4*)(Wq + row*64 + 8*g);  aq0 = mk8(v4[0], v4[1]);
        v4 = (const float4*)(Wq + row*64 + 32 + 8*g); aq1 = mk8(v4[0], v4[1]);
        v4 = (const float4*)(Wk + row*64 + 8*g);  ak0 = mk8(v4[0], v4[1]);
        v4 = (const float4*)(Wk + row*64 + 32 + 8*g); ak1 = mk8(v4[0], v4[1]);
        v4 = (const float4*)(Wv + row*64 + 8*g);  av0 = mk8(v4[0], v4[1]);
        v4 = (const float4*)(Wv + row*64 + 32 + 8*g); av1 = mk8(v4[0], v4[1]);
    }
    // per-lane bn1/bias constants for output rows o = 16w + 4g + r
    float s1v[4], t1v[4], bqv[4], bkv[4], bvv[4];
#pragma unroll
    for (int r=0;r<4;++r){
        const int o = 16*w + 4*g + r;
        const float s = bn1[o]*rsqrtf(bn1[192+o]+EPSV);
        s1v[r]=s; t1v[r]=fmaf(-bn1[128+o], s, bn1[64+o]);
        bqv[r]=bq[o]; bkv[r]=bk[o]; bvv[r]=bv[o];
    }
    __syncthreads();

    // ---- GEMM1: f = relu(bn1(W1 @ feat)) -> lf ----
#pragma unroll
    for (int st=0; st<4; ++st){
        const int pt = st*16 + i16;
        bf16x8 b1 = *(const bf16x8*)((const unsigned short*)lfeat + pt*40 + 8*g);
        f32x4 d = {0.f,0.f,0.f,0.f};
        d = __builtin_amdgcn_mfma_f32_16x16x32_bf16(a1, b1, d, 0,0,0);
        const float f0 = fmaxf(fmaf(d[0], s1v[0], t1v[0]), 0.f);
        const float f1 = fmaxf(fmaf(d[1], s1v[1], t1v[1]), 0.f);
        const float f2 = fmaxf(fmaf(d[2], s1v[2], t1v[2]), 0.f);
        const float f3 = fmaxf(fmaf(d[3], s1v[3], t1v[3]), 0.f);
        const int oh = 8*w + 2*g;            // (16w+4g)/2
        lf[pt*36 + oh    ] = pk2(f0, f1);
        lf[pt*36 + oh + 1] = pk2(f2, f3);
    }
    __syncthreads();

    // ---- GEMM2: q/k/v = W @ f + b -> lbuf (bf16 pairs) ----
#pragma unroll
    for (int st=0; st<4; ++st){
        const int pt = st*16 + i16;
        bf16x8 b20 = *(const bf16x8*)(lf + pt*36 + 4*g);        // f chs 8g..8g+7
        bf16x8 b21 = *(const bf16x8*)(lf + pt*36 + 16 + 4*g);   // f chs 32+8g..+7
        f32x4 dq = {bqv[0],bqv[1],bqv[2],bqv[3]};
        f32x4 dk = {bkv[0],bkv[1],bkv[2],bkv[3]};
        f32x4 dv = {bvv[0],bvv[1],bvv[2],bvv[3]};
        dq = __builtin_amdgcn_mfma_f32_16x16x32_bf16(aq0, b20, dq, 0,0,0);
        dq = __builtin_amdgcn_mfma_f32_16x16x32_bf16(aq1, b21, dq, 0,0,0);
        dk = __builtin_amdgcn_mfma_f32_16x16x32_bf16(ak0, b20, dk, 0,0,0);
        dk = __builtin_amdgcn_mfma_f32_16x16x32_bf16(ak1, b21, dk, 0,0,0);
        dv = __builtin_amdgcn_mfma_f32_16x16x32_bf16(av0, b20, dv, 0,0,0);
        dv = __builtin_amdgcn_mfma_f32_16x16x32_bf16(av1, b21, dv, 0,0,0);
        const int pbase = pt*100;
        const int oh = 8*w + 2*g;
        lbuf[pbase + oh         ] = pk2(dq[0], dq[1]);
        lbuf[pbase + oh + 1     ] = pk2(dq[2], dq[3]);
        lbuf[pbase + 32 + oh    ] = pk2(dk[0], dk[1]);
        lbuf[pbase + 32 + oh + 1] = pk2(dk[2], dk[3]);
        lbuf[pbase + 64 + oh    ] = pk2(dv[0], dv[1]);
        lbuf[pbase + 64 + oh + 1] = pk2(dv[2], dv[3]);
    }
    __syncthreads();

    // ---- coalesced copy-out: wave0 -> f, wave1 -> q, waves2/3 -> kv ----
    if (w == 0){
#pragma unroll
        for (int c=0;c<8;++c){
            const int off = c*256 + 4*lane;          // 0..2047
            const int pt = off>>5, j = off&31;
            *(uint4*)(f_pk + (size_t)p0*32 + off) = *(const uint4*)(lf + pt*36 + j);
        }
    } else if (w == 1){
#pragma unroll
        for (int c=0;c<8;++c){
            const int off = c*256 + 4*lane;
            const int pt = off>>5, j = off&31;
            *(uint4*)(q_pk + (size_t)p0*32 + off) = *(const uint4*)(lbuf + pt*100 + j);
        }
    } else {
#pragma unroll
        for (int c=0;c<8;++c){
            const int off = (w-2)*2048 + c*256 + 4*lane;   // 0..4095
            const int pt = off>>6, j = off&63;
            *(uint4*)(kv_u + (size_t)p0*64 + off) = *(const uint4*)(lbuf + pt*100 + 32 + j);
        }
    }
}

// ---------------- Kernel 2: gather + attention + epilogue. 8 lanes/point. ----------------
__global__ __launch_bounds__(256) void attn_kernel(
    const float* __restrict__ xyz, const int* __restrict__ nidx,
    const float* __restrict__ Wp1, const float* __restrict__ bnp1,
    const float* __restrict__ Wp2, const float* __restrict__ bp2,
    const float* __restrict__ bnw0,
    const float* __restrict__ Ww1, const float* __restrict__ bnw1,
    const float* __restrict__ Ww2, const float* __restrict__ bw2,
    const float* __restrict__ bn_mid,
    const float* __restrict__ W2, const float* __restrict__ bn2,
    const unsigned* __restrict__ f_pk, const unsigned* __restrict__ q_pk,
    const unsigned short* __restrict__ kv_ws,
    float* __restrict__ out)
{
    __shared__ unsigned lww1h[8*32];   // Ww1 bf16-packed
    __shared__ float lw2[64*68];       // W2 rows stride 68 (conflict-free interleaved reads)
    __shared__ float lout[64*33];      // output transpose: [channel][point], stride 33
    const int t = threadIdx.x;
    if (t < 256){
        const int j = t>>5, c2 = t&31;
        lww1h[j*32+c2] = pk2(Ww1[j*64+2*c2], Ww1[j*64+2*c2+1]);
    }
#pragma unroll
    for (int r=0;r<16;++r){
        const int idx = t + r*256;
        const int o = idx>>6, c = idx&63;
        lw2[o*68+c] = W2[idx];
    }
    __syncthreads();

    const int tid = blockIdx.x*256 + t;
    const int ll  = t & 7;
    const int p   = tid >> 3;
    const int b   = p >> 14;
    const int obase = (t & 63) & 56;

    float wp1[9];
#pragma unroll
    for (int u=0;u<9;++u) wp1[u] = rfl(Wp1[u]);
    float sp1[3], tp1[3];
#pragma unroll
    for (int o=0;o<3;++o){
        const float s = bnp1[o]*rsqrtf(bnp1[9+o]+EPSV);
        sp1[o]=rfl(s); tp1[o]=rfl(fmaf(-bnp1[6+o], s, bnp1[3+o]));
    }
    float sw1[8], tw1[8];
#pragma unroll
    for (int j=0;j<8;++j){
        const float s = bnw1[j]*rsqrtf(bnw1[24+j]+EPSV);
        sw1[j]=rfl(s); tw1[j]=rfl(fmaf(-bnw1[16+j], s, bnw1[8+j]));
    }
    float wp2f[24];
#pragma unroll
    for (int u=0;u<6;++u){
        const float4 w = ((const float4*)Wp2)[6*ll+u];
        wp2f[4*u]=w.x; wp2f[4*u+1]=w.y; wp2f[4*u+2]=w.z; wp2f[4*u+3]=w.w;
    }
    float ww2r[8]; float bwr;
    {
        const float4 a = ((const float4*)Ww2)[2*ll], c = ((const float4*)Ww2)[2*ll+1];
        ww2r[0]=a.x; ww2r[1]=a.y; ww2r[2]=a.z; ww2r[3]=a.w;
        ww2r[4]=c.x; ww2r[5]=c.y; ww2r[6]=c.z; ww2r[7]=c.w;
        bwr = bw2[ll];
    }
    // fold bnw0 + q + bp2 into qc (q now bf16-packed: one uint4)
    float s0[8], qc[8];
    {
        float qv[8], bpv[8];
        const uint4 qu = *(const uint4*)(q_pk + (size_t)p*32 + 4*ll);
        unpk(qu.x, qv[0], qv[1]); unpk(qu.y, qv[2], qv[3]);
        unpk(qu.z, qv[4], qv[5]); unpk(qu.w, qv[6], qv[7]);
        const float4* bp = (const float4*)(bp2 + 8*ll);
        const float4 b0 = bp[0], b1 = bp[1];
        bpv[0]=b0.x;bpv[1]=b0.y;bpv[2]=b0.z;bpv[3]=b0.w; bpv[4]=b1.x;bpv[5]=b1.y;bpv[6]=b1.z;bpv[7]=b1.w;
        const float4* g4 = (const float4*)(bnw0 + 8*ll);
        const float4 g0=g4[0], g1=g4[1];
        const float4* be4 = (const float4*)(bnw0 + 64 + 8*ll);
        const float4 e0=be4[0], e1=be4[1];
        const float4* m4 = (const float4*)(bnw0 + 128 + 8*ll);
        const float4 m0=m4[0], m1=m4[1];
        const float4* v4 = (const float4*)(bnw0 + 192 + 8*ll);
        const float4 v0=v4[0], v1=v4[1];
        const float gg[8]={g0.x,g0.y,g0.z,g0.w,g1.x,g1.y,g1.z,g1.w};
        const float bb[8]={e0.x,e0.y,e0.z,e0.w,e1.x,e1.y,e1.z,e1.w};
        const float mm[8]={m0.x,m0.y,m0.z,m0.w,m1.x,m1.y,m1.z,m1.w};
        const float vv[8]={v0.x,v0.y,v0.z,v0.w,v1.x,v1.y,v1.z,v1.w};
#pragma unroll
        for (int i=0;i<8;++i){
            const float s = gg[i]*rsqrtf(vv[i]+EPSV);
            s0[i]=s;
            qc[i]=fmaf(-mm[i], s, bb[i]) + s*(bpv[i]-qv[i]);
        }
    }

    float m[8], l[8], acc[8];
#pragma unroll
    for (int j=0;j<8;++j){ m[j]=-3.0e38f; l[j]=0.f; acc[j]=0.f; }

    const int* nip = nidx + p*16;

#pragma unroll 2
    for (int k=0;k<KNBR;++k){
        const int ni   = nip[k];
        const int rowb = (b<<14) + ni;
        const uint4* kvp = (const uint4*)(kv_ws + (size_t)rowb*128);
        const uint4 ku = kvp[ll];
        const uint4 vu = kvp[8+ll];
        const float* xp = xyz + rowb*3;
        const float x0=xp[0], x1=xp[1], x2v=xp[2];

        float t3[3];
#pragma unroll
        for (int o=0;o<3;++o){
            const float u = fmaf(wp1[3*o], x0, fmaf(wp1[3*o+1], x1, wp1[3*o+2]*x2v));
            t3[o] = fmaxf(fmaf(u, sp1[o], tp1[o]), 0.f);
        }
        float kf[8];
        unpk(ku.x, kf[0], kf[1]); unpk(ku.y, kf[2], kf[3]);
        unpk(ku.z, kf[4], kf[5]); unpk(ku.w, kf[6], kf[7]);
        float pr[8], wl[8];
#pragma unroll
        for (int i=0;i<8;++i){
            pr[i] = fmaf(wp2f[3*i], t3[0], fmaf(wp2f[3*i+1], t3[1], wp2f[3*i+2]*t3[2]));
            wl[i] = lrelu_(fmaf(s0[i], kf[i]+pr[i], qc[i]));
        }
        float y[8];
#pragma unroll
        for (int j=0;j<8;++j){
            const uint4 w = *(const uint4*)(lww1h + j*32 + 4*ll);
            float a,c, yy;
            unpk(w.x,a,c); yy  = a*wl[0];        yy = fmaf(c,wl[1],yy);
            unpk(w.y,a,c); yy = fmaf(a,wl[2],yy); yy = fmaf(c,wl[3],yy);
            unpk(w.z,a,c); yy = fmaf(a,wl[4],yy); yy = fmaf(c,wl[5],yy);
            unpk(w.w,a,c); yy = fmaf(a,wl[6],yy); yy = fmaf(c,wl[7],yy);
            yy += __shfl_xor(yy, 1);
            yy += __shfl_xor(yy, 2);
            yy += __shfl_xor(yy, 4);
            y[j] = yy;
        }
#pragma unroll
        for (int j=0;j<8;++j) y[j] = fmaxf(fmaf(y[j], sw1[j], tw1[j]), 0.f);
        float w2own = bwr;
#pragma unroll
        for (int j=0;j<8;++j) w2own = fmaf(ww2r[j], y[j], w2own);
        float w2[8];
        w2[0]=__shfl(w2own, obase+0); w2[1]=__shfl(w2own, obase+1);
        w2[2]=__shfl(w2own, obase+2); w2[3]=__shfl(w2own, obase+3);
        w2[4]=__shfl(w2own, obase+4); w2[5]=__shfl(w2own, obase+5);
        w2[6]=__shfl(w2own, obase+6); w2[7]=__shfl(w2own, obase+7);

        float sc[8], e[8];
#pragma unroll
        for (int j=0;j<8;++j){
            const float mn = fmaxf(m[j], w2[j]);
            sc[j] = __expf(m[j]-mn);
            e[j]  = __expf(w2[j]-mn);
            l[j]  = fmaf(l[j], sc[j], e[j]);
            m[j]  = mn;
        }
        float vf[8];
        unpk(vu.x, vf[0], vf[1]); unpk(vu.y, vf[2], vf[3]);
        unpk(vu.z, vf[4], vf[5]); unpk(vu.w, vf[6], vf[7]);
#pragma unroll
        for (int i=0;i<8;++i)
            acc[i] = fmaf(acc[i], sc[i], (vf[i]+pr[i])*e[i]);
    }

    // normalize + deferred bp2 + bn_mid + lrelu (bp2 reloaded here, L1-hot)
    float xm[8];
    {
        const float4* bp = (const float4*)(bp2 + 8*ll);
        const float4 b0 = bp[0], b1 = bp[1];
        const float bpv[8]={b0.x,b0.y,b0.z,b0.w,b1.x,b1.y,b1.z,b1.w};
        const float4* g4 = (const float4*)(bn_mid + 8*ll);
        const float4 g0=g4[0], g1=g4[1];
        const float4* be4 = (const float4*)(bn_mid + 64 + 8*ll);
        const float4 e0=be4[0], e1=be4[1];
        const float4* m4 = (const float4*)(bn_mid + 128 + 8*ll);
        const float4 m0=m4[0], m1=m4[1];
        const float4* v4 = (const float4*)(bn_mid + 192 + 8*ll);
        const float4 v0=v4[0], v1=v4[1];
        const float gg[8]={g0.x,g0.y,g0.z,g0.w,g1.x,g1.y,g1.z,g1.w};
        const float bb[8]={e0.x,e0.y,e0.z,e0.w,e1.x,e1.y,e1.z,e1.w};
        const float mm[8]={m0.x,m0.y,m0.z,m0.w,m1.x,m1.y,m1.z,m1.w};
        const float vv[8]={v0.x,v0.y,v0.z,v0.w,v1.x,v1.y,v1.z,v1.w};
#pragma unroll
        for (int i=0;i<8;++i){
            const float s = gg[i]*rsqrtf(vv[i]+EPSV);
            const float tt = fmaf(-mm[i], s, bb[i]);
            const float xx = fmaf(acc[i], 1.f/l[i], bpv[i]);
            xm[i] = lrelu_(fmaf(xx, s, tt));
        }
    }
    float Zx0[4],Zx1[4],Zx2[4],Zx3[4],Zx4[4],Zx5[4],Zx6[4],Zx7[4];
    float Zx8[4],Zx9[4],Zx10[4],Zx11[4],Zx12[4],Zx13[4],Zx14[4],Zx15[4];
#pragma unroll
    for (int r=0;r<4;++r){
        Zx0[r] =__shfl(xm[r],   obase+0); Zx1[r] =__shfl(xm[4+r], obase+0);
        Zx2[r] =__shfl(xm[r],   obase+1); Zx3[r] =__shfl(xm[4+r], obase+1);
        Zx4[r] =__shfl(xm[r],   obase+2); Zx5[r] =__shfl(xm[4+r], obase+2);
        Zx6[r] =__shfl(xm[r],   obase+3); Zx7[r] =__shfl(xm[4+r], obase+3);
        Zx8[r] =__shfl(xm[r],   obase+4); Zx9[r] =__shfl(xm[4+r], obase+4);
        Zx10[r]=__shfl(xm[r],   obase+5); Zx11[r]=__shfl(xm[4+r], obase+5);
        Zx12[r]=__shfl(xm[r],   obase+6); Zx13[r]=__shfl(xm[4+r], obase+6);
        Zx14[r]=__shfl(xm[r],   obase+7); Zx15[r]=__shfl(xm[4+r], obase+7);
    }
#define DOT4(W4, Z) (fmaf((W4).w, (Z)[3], fmaf((W4).z, (Z)[2], fmaf((W4).y, (Z)[1], (W4).x*(Z)[0]))))
    const int pidx = t >> 3;                 // point index within block (0..31)
#pragma unroll
    for (int i=0;i<8;++i){
        const int o = 8*i+ll;
        const float4* row = (const float4*)(lw2 + o*68);
        float hs = 0.f;
        hs += DOT4(row[0],  Zx0);  hs += DOT4(row[1],  Zx1);
        hs += DOT4(row[2],  Zx2);  hs += DOT4(row[3],  Zx3);
        hs += DOT4(row[4],  Zx4);  hs += DOT4(row[5],  Zx5);
        hs += DOT4(row[6],  Zx6);  hs += DOT4(row[7],  Zx7);
        hs += DOT4(row[8],  Zx8);  hs += DOT4(row[9],  Zx9);
        hs += DOT4(row[10], Zx10); hs += DOT4(row[11], Zx11);
        hs += DOT4(row[12], Zx12); hs += DOT4(row[13], Zx13);
        hs += DOT4(row[14], Zx14); hs += DOT4(row[15], Zx15);
        const float s2 = bn2[o]*rsqrtf(bn2[192+o]+EPSV);
        const float t2 = fmaf(-bn2[128+o], s2, bn2[64+o]);
        const float x2r = fmaf(hs, s2, t2);
        // residual f from bf16-packed f_pk: uint (o>>1) = (4i + ll/2), select lo/hi by ll&1
        const unsigned fu = f_pk[(size_t)p*32 + 4*i + (ll>>1)];
        float flo, fhi; unpk(fu, flo, fhi);
        const float fo = (ll & 1) ? fhi : flo;
        lout[o*33 + pidx] = lrelu_(fo + x2r);
    }
#undef DOT4
    __syncthreads();
    // coalesced store: thread t -> channel t>>2, points (t&3)*8 .. +7 (two dwordx4)
    {
        const int oc = t >> 2;
        const int j0 = (t & 3) * 8;
        const int p0 = blockIdx.x * 32;          // block's first point
        const int bb = p0 >> 14;
        const int n0 = p0 & (NPTS-1);
        float v0[4], v1[4];
#pragma unroll
        for (int r=0;r<4;++r){ v0[r] = lout[oc*33 + j0 + r]; v1[r] = lout[oc*33 + j0 + 4 + r]; }
        float* op = out + (size_t)(bb*64 + oc)*NPTS + n0 + j0;
        ((float4*)op)[0] = make_float4(v0[0],v0[1],v0[2],v0[3]);
        ((float4*)op)[1] = make_float4(v1[0],v1[1],v1[2],v1[3]);
    }
}

extern "C" void kernel_launch(void* const* d_in, const int* in_sizes, int n_in,
                              void* d_out, int out_size, void* d_ws, size_t ws_size,
                              hipStream_t stream) {
    const float* feature = (const float*)d_in[0];
    const float* xyz     = (const float*)d_in[1];
    const float* W1      = (const float*)d_in[2];
    const float* bn1     = (const float*)d_in[3];
    const float* Wq      = (const float*)d_in[4];
    const float* bq      = (const float*)d_in[5];
    const float* Wk      = (const float*)d_in[6];
    const float* bk      = (const float*)d_in[7];
    const float* Wv      = (const float*)d_in[8];
    const float* bv      = (const float*)d_in[9];
    const float* Wp1     = (const float*)d_in[10];
    const float* bnp1    = (const float*)d_in[11];
    const float* Wp2     = (const float*)d_in[12];
    const float* bp2     = (const float*)d_in[13];
    const float* bnw0    = (const float*)d_in[14];
    const float* Ww1     = (const float*)d_in[15];
    const float* bnw1    = (const float*)d_in[16];
    const float* Ww2     = (const float*)d_in[17];
    const float* bw2     = (const float*)d_in[18];
    const float* bn_mid  = (const float*)d_in[19];
    const float* W2      = (const float*)d_in[20];
    const float* bn2     = (const float*)d_in[21];
    const int*   nidx    = (const int*)d_in[22];
    float* out = (float*)d_out;

    // ws: f_pk (4MB bf16 pairs) | q_pk (4MB) | kv (8MB bf16, k||v per point)
    unsigned* ws = (unsigned*)d_ws;
    unsigned* f_pk = ws;
    unsigned* q_pk = ws + 1048576;
    unsigned* kv_u = ws + 2097152;
    unsigned short* kv_ws = (unsigned short*)kv_u;

    qkvf_kernel<<<512, 256, 0, stream>>>(feature, W1, bn1, Wq, bq, Wk, bk, Wv, bv,
                                         f_pk, q_pk, kv_u);
    attn_kernel<<<1024, 256, 0, stream>>>(xyz, nidx, Wp1, bnp1, Wp2, bp2, bnw0,
                                          Ww1, bnw1, Ww2, bw2, bn_mid, W2, bn2,
                                          f_pk, q_pk, kv_ws, out);
}